// Round 10
// baseline (162.311 us; speedup 1.0000x reference)
//
#include <hip/hip_runtime.h>
#include <hip/hip_bf16.h>

#define B_ 16
#define C_ 512
#define N_ 1024
#define KL 256
#define HEADS_ 8
#define DH_ 64

typedef __attribute__((ext_vector_type(8))) short bf16x8;
typedef __attribute__((ext_vector_type(4))) float f32x4;
typedef __attribute__((ext_vector_type(16))) float f32x16;

__device__ inline short f2bf(float f) {
  __hip_bfloat16 h = __float2bfloat16(f);
  return *reinterpret_cast<short*>(&h);
}

__device__ inline float bf2f(short s) {
  union { unsigned int u; float f; } c;
  c.u = ((unsigned int)(unsigned short)s) << 16;
  return c.f;
}

__device__ inline void gload16(const void* g, void* l) {
  __builtin_amdgcn_global_load_lds(
      (const __attribute__((address_space(1))) void*)g,
      (__attribute__((address_space(3))) void*)l, 16, 0, 0);
}

// ---------------- GroupNorm stats pass 1: 1024 blocks
__global__ __launch_bounds__(256) void gn_stats1(const float* __restrict__ x,
                                                 float2* __restrict__ part) {
  const int tid = threadIdx.x;
  const int lane = tid & 63, wid = tid >> 6;
  const float4* b4 = (const float4*)(x + (long long)blockIdx.x * 8192);
  float s = 0.f, sq = 0.f;
#pragma unroll
  for (int j = 0; j < 8; ++j) {
    float4 v = b4[tid + j * 256];
    s += v.x + v.y + v.z + v.w;
    sq += v.x * v.x + v.y * v.y + v.z * v.z + v.w * v.w;
  }
#pragma unroll
  for (int m = 1; m < 64; m <<= 1) {
    s += __shfl_xor(s, m);
    sq += __shfl_xor(sq, m);
  }
  __shared__ float red[8];
  if (lane == 0) { red[wid] = s; red[4 + wid] = sq; }
  __syncthreads();
  if (tid == 0)
    part[blockIdx.x] = make_float2(red[0] + red[1] + red[2] + red[3],
                                   red[4] + red[5] + red[6] + red[7]);
}

// ---------------- GroupNorm apply (stats finalize inlined per block)
__global__ __launch_bounds__(256) void gn_apply(
    const float* __restrict__ x, const float* __restrict__ gamma,
    const float* __restrict__ beta, const float2* __restrict__ part,
    short* __restrict__ xnc, short* __restrict__ xnT) {
  const int t = blockIdx.x, g = blockIdx.y, b = blockIdx.z;
  float s = 0.f, sq = 0.f;
#pragma unroll
  for (int j = 0; j < 8; ++j) {
    float2 p = part[(b * 8 + g) * 8 + j];
    s += p.x; sq += p.y;
  }
  const float mu = s * (1.f / 65536.f);
  const float var = sq * (1.f / 65536.f) - mu * mu;
  const float rs = rsqrtf(var + 1e-5f);

  __shared__ short tile[64 * 65];
#pragma unroll
  for (int i = 0; i < 4; ++i) {
    const int idx = threadIdx.x + i * 256;
    const int cl = idx >> 4;
    const int nl0 = (idx & 15) * 4;
    const int ch = g * 64 + cl;
    const long long gi = ((long long)(b * C_ + ch)) * N_ + t * 64 + nl0;
    const float4 v = *(const float4*)(x + gi);
    const float gm = gamma[ch], bt = beta[ch];
    short s0 = f2bf((v.x - mu) * rs * gm + bt);
    short s1 = f2bf((v.y - mu) * rs * gm + bt);
    short s2 = f2bf((v.z - mu) * rs * gm + bt);
    short s3 = f2bf((v.w - mu) * rs * gm + bt);
    short4 pk; pk.x = s0; pk.y = s1; pk.z = s2; pk.w = s3;
    *(short4*)(xnc + gi) = pk;
    tile[cl * 65 + nl0] = s0;
    tile[cl * 65 + nl0 + 1] = s1;
    tile[cl * 65 + nl0 + 2] = s2;
    tile[cl * 65 + nl0 + 3] = s3;
  }
  __syncthreads();

#pragma unroll
  for (int i = 0; i < 4; ++i) {
    const int idx = threadIdx.x + i * 256;
    const int cl0 = (idx & 15) * 4;
    const int nl = idx >> 4;
    short4 pk;
    pk.x = tile[(cl0 + 0) * 65 + nl];
    pk.y = tile[(cl0 + 1) * 65 + nl];
    pk.z = tile[(cl0 + 2) * 65 + nl];
    pk.w = tile[(cl0 + 3) * 65 + nl];
    *(short4*)(xnT + ((long long)b * N_ + t * 64 + nl) * C_ + g * 64 + cl0) = pk;
  }
}

// ---------------- ALL weight prep in ONE launch (266 blocks)
__global__ __launch_bounds__(256) void prep_all(
    const float* __restrict__ w_qkv, const float* __restrict__ w_proj,
    const float* __restrict__ w_o, const float* __restrict__ E,
    const float* __restrict__ F, const float* __restrict__ b_o,
    const float* __restrict__ b_proj,
    short* __restrict__ wqkv_b, short* __restrict__ wproj_b,
    short* __restrict__ woT_b, short* __restrict__ Et, short* __restrict__ Ft,
    float* __restrict__ esum, float* __restrict__ fsum, float* __restrict__ b2) {
  __shared__ float tl[64 * 65];
  int bid = blockIdx.x;
  const int tid = threadIdx.x;

  if (bid < 64) {  // dtype converts
    const float4* src;
    short4* dst;
    if (bid < 48) { src = (const float4*)w_qkv + bid * 4096; dst = (short4*)wqkv_b + bid * 4096; }
    else          { src = (const float4*)w_proj + (bid - 48) * 4096; dst = (short4*)wproj_b + (bid - 48) * 4096; }
#pragma unroll
    for (int i = 0; i < 16; ++i) {
      float4 v = src[tid + i * 256];
      short4 p; p.x = f2bf(v.x); p.y = f2bf(v.y); p.z = f2bf(v.z); p.w = f2bf(v.w);
      dst[tid + i * 256] = p;
    }
    return;
  }
  bid -= 64;
  if (bid < 192) {  // transposes: w_o (64), E (64), F (64)
    const float* src; short* dst; int sN, tr, tc;
    if (bid < 64) { src = w_o; dst = woT_b; sN = 512; tr = bid >> 3; tc = bid & 7; }
    else if (bid < 128) { src = E; dst = Et; sN = 256; tr = (bid - 64) & 15; tc = (bid - 64) >> 4; }
    else { src = F; dst = Ft; sN = 256; tr = (bid - 128) & 15; tc = (bid - 128) >> 4; }
    const int R = (sN == 512) ? 512 : 1024;
#pragma unroll 4
    for (int i = 0; i < 16; ++i) {
      const int idx = tid + i * 256;
      const int rl = idx >> 6, cl = idx & 63;
      tl[rl * 65 + cl] = src[(tr * 64 + rl) * sN + tc * 64 + cl];
    }
    __syncthreads();
#pragma unroll 4
    for (int i = 0; i < 16; ++i) {
      const int idx = tid + i * 256;
      const int cl = idx >> 6, rl = idx & 63;
      dst[(tc * 64 + cl) * R + tr * 64 + rl] = f2bf(tl[rl * 65 + cl]);
    }
    return;
  }
  bid -= 192;
  if (bid < 8) {  // colsum
    __shared__ float cs[4][64];
    const float* src = (bid < 4) ? E : F;
    float* dst = (bid < 4) ? esum : fsum;
    const int cb = (bid & 3) * 64;
    const int col = cb + (tid & 63), seg = tid >> 6;
    float s = 0.f;
    for (int n = seg * 256; n < seg * 256 + 256; ++n) s += src[n * 256 + col];
    cs[seg][tid & 63] = s;
    __syncthreads();
    if (tid < 64) dst[cb + tid] = cs[0][tid] + cs[1][tid] + cs[2][tid] + cs[3][tid];
    return;
  }
  bid -= 8;
  {  // b2
    const int o = bid * 256 + tid;
    float s = b_proj[o];
    for (int m = 0; m < 512; ++m) s += w_proj[o * 512 + m] * b_o[m];
    b2[o] = s;
  }
}

// ---------------- multi-job GEMM. CRITICAL: no GJob struct copy in the kernel —
// a conditionally-assigned aggregate goes to SCRATCH and every field read in the
// hot loop becomes a ~500-cycle scratch load (rule #20; r8/r9's 81-us disaster).
// All fields selected via uniform scalar ternaries -> s_cselect, SGPR-resident.
struct GJob {
  const short* A; const short* Bt; void* C;
  const float* bias; const float* bias2; const short* resid;
  int M, Nn, Kd;
  long long sA, sB, sC;
  int gx, gy, nblk;
  int bias_mode;  // 0 none, 1 bias[row], 2 bias[col], 3 bias[row]*bias2[col]
  int out_bf16, resid_on;
};

__global__ __launch_bounds__(256) void gemm_multi(GJob j0, GJob j1, GJob j2, int njobs) {
  int bid = blockIdx.x;
  int sel = 0;
  if (njobs > 1 && bid >= j0.nblk) {
    bid -= j0.nblk; sel = 1;
    if (njobs > 2 && bid >= j1.nblk) { bid -= j1.nblk; sel = 2; }
  }
#define PICK(f) (sel == 0 ? j0.f : (sel == 1 ? j1.f : j2.f))
  const short* JA    = PICK(A);
  const short* JBt   = PICK(Bt);
  void* JC           = PICK(C);
  const float* Jbias = PICK(bias);
  const float* Jbias2= PICK(bias2);
  const short* Jres  = PICK(resid);
  const int Nn       = PICK(Nn);
  const int Kd       = PICK(Kd);
  const long long sA = PICK(sA);
  const long long sB = PICK(sB);
  const long long sC = PICK(sC);
  const int gx       = PICK(gx);
  const int gy       = PICK(gy);
  const int nblk     = PICK(nblk);
  const int bias_mode= PICK(bias_mode);
  const int out_bf16 = PICK(out_bf16);
  const int resid_on = PICK(resid_on);
#undef PICK

  const int cpx = nblk >> 3;
  int w = (bid & 7) * cpx + (bid >> 3);
  const int mx = w % gx; w /= gx;
  const int ny = w % gy;
  const int bz = w / gy;

  const int m0 = mx * 128;
  const int n0 = ny * 128;
  const short* Ab = JA + bz * sA;
  const short* Bb = JBt + bz * sB;
  const int tid = threadIdx.x;
  const int lane = tid & 63;
  const int wid = tid >> 6;
  const int wm = wid >> 1, wn = wid & 1;

  __shared__ __align__(16) short As[2][128 * 64];
  __shared__ __align__(16) short Bs[2][128 * 64];

  auto stage = [&](int bufi, int kt) {
#pragma unroll
    for (int r = 0; r < 4; ++r) {
      const int dbase = r * 4096 + wid * 1024;
      const int dbyte = dbase + (lane << 4);
      const int row = dbyte >> 7;
      const int chunk = ((dbyte >> 4) & 7) ^ (row & 7);
      gload16(Ab + (long long)(m0 + row) * Kd + kt + chunk * 8, (char*)As[bufi] + dbase);
      gload16(Bb + (long long)(n0 + row) * Kd + kt + chunk * 8, (char*)Bs[bufi] + dbase);
    }
  };

  f32x4 acc[4][4] = {};

  const int nk = Kd >> 6;
  stage(0, 0);
  stage(1, 64);

  for (int i = 0; i < nk; ++i) {
    const int cur = i & 1;
    if (i + 1 < nk) asm volatile("s_waitcnt vmcnt(8)" ::: "memory");
    else            asm volatile("s_waitcnt vmcnt(0)" ::: "memory");
    __builtin_amdgcn_s_barrier();
    __builtin_amdgcn_sched_barrier(0);
#pragma unroll
    for (int kk = 0; kk < 2; ++kk) {
      bf16x8 af[4], bfr[4];
#pragma unroll
      for (int mi = 0; mi < 4; ++mi) {
        int row = wm * 64 + mi * 16 + (lane & 15);
        int chunk = (kk * 4 + (lane >> 4)) ^ (row & 7);
        af[mi] = *(const bf16x8*)(As[cur] + row * 64 + chunk * 8);
      }
#pragma unroll
      for (int ni = 0; ni < 4; ++ni) {
        int row = wn * 64 + ni * 16 + (lane & 15);
        int chunk = (kk * 4 + (lane >> 4)) ^ (row & 7);
        bfr[ni] = *(const bf16x8*)(Bs[cur] + row * 64 + chunk * 8);
      }
#pragma unroll
      for (int mi = 0; mi < 4; ++mi)
#pragma unroll
        for (int ni = 0; ni < 4; ++ni)
          acc[mi][ni] = __builtin_amdgcn_mfma_f32_16x16x32_bf16(af[mi], bfr[ni], acc[mi][ni], 0, 0, 0);
    }
    __builtin_amdgcn_s_barrier();
    __builtin_amdgcn_sched_barrier(0);
    if (i + 2 < nk) stage(cur, (i + 2) << 6);
  }

#pragma unroll
  for (int mi = 0; mi < 4; ++mi) {
#pragma unroll
    for (int ni = 0; ni < 4; ++ni) {
      const int row = m0 + wm * 64 + mi * 16 + ((lane >> 4) << 2);
      const int col = n0 + wn * 64 + ni * 16 + (lane & 15);
      f32x4 v = acc[mi][ni];
#pragma unroll
      for (int j = 0; j < 4; ++j) {
        float val = v[j];
        if (bias_mode == 1) val += Jbias[row + j];
        else if (bias_mode == 2) val += Jbias[col];
        else if (bias_mode == 3) val += Jbias[row + j] * Jbias2[col];
        const long long ci = (long long)bz * sC + (long long)(row + j) * Nn + col;
        if (resid_on) val += bf2f(Jres[ci]);
        if (out_bf16) ((short*)JC)[ci] = f2bf(val);
        else ((float*)JC)[ci] = val;
      }
    }
  }
}

// ---------------- fused Linformer attention, 32x32 swapped-QK, in-register softmax
__global__ __launch_bounds__(512, 4) void attn_fused32(
    const short* __restrict__ q, const short* __restrict__ kp,
    const short* __restrict__ vp, short* __restrict__ o) {
  const int qt = blockIdx.x;
  const int h = blockIdx.y;
  const int b = blockIdx.z;
  const int tid = threadIdx.x;
  const int lane = tid & 63;
  const int wid = tid >> 6;
  const int nlo = lane & 31;
  const int hi = lane >> 5;

  __shared__ __align__(16) short kbuf[256 * 64];
  __shared__ __align__(16) short vbuf[64 * 256];

  {
    const short* base = kp + (long long)b * (KL * C_) + h * DH_;
#pragma unroll
    for (int i = 0; i < 4; ++i) {
      const int dbyte = (i * 512 + tid) * 16;
      const int row = dbyte >> 7;
      const int chunk = ((dbyte >> 4) & 7) ^ (row & 7);
      gload16(base + row * C_ + chunk * 8, (char*)kbuf + dbyte);
    }
  }
  {
    const short* base = vp + ((long long)b * C_ + h * DH_) * KL;
#pragma unroll
    for (int i = 0; i < 4; ++i) {
      const int dbyte = (i * 512 + tid) * 16;
      const int row = dbyte >> 9;
      const int chunk = ((dbyte >> 4) & 31) ^ (row & 7);
      gload16(base + row * KL + chunk * 8, (char*)vbuf + dbyte);
    }
  }

  const int n0 = qt * 256 + wid * 32;
  bf16x8 bq[4];
  {
    const short* qb = q + ((long long)b * N_ + n0 + nlo) * C_ + h * DH_ + hi * 8;
#pragma unroll
    for (int dk = 0; dk < 4; ++dk) bq[dk] = *(const bf16x8*)(qb + dk * 16);
  }
  __syncthreads();

  f32x16 oa0, oa1;
#pragma unroll
  for (int r = 0; r < 16; ++r) { oa0[r] = 0.f; oa1[r] = 0.f; }
  float mrun = -1e30f, lrun = 0.f;

#pragma unroll
  for (int kb = 0; kb < 8; ++kb) {
    f32x16 s;
#pragma unroll
    for (int r = 0; r < 16; ++r) s[r] = 0.f;
#pragma unroll
    for (int dk = 0; dk < 4; ++dk) {
      const int row = kb * 32 + nlo;
      bf16x8 ak = *(const bf16x8*)(kbuf + row * 64 + (((dk * 2 + hi) ^ (nlo & 7)) * 8));
      s = __builtin_amdgcn_mfma_f32_32x32x16_bf16(ak, bq[dk], s, 0, 0, 0);
    }
    float lm = -1e30f;
#pragma unroll
    for (int r = 0; r < 16; ++r) { s[r] *= 0.125f; lm = fmaxf(lm, s[r]); }
    lm = fmaxf(lm, __shfl_xor(lm, 32));
    const float mnew = fmaxf(mrun, lm);
    const float sc_old = __expf(mrun - mnew);
    float ls = 0.f;
#pragma unroll
    for (int r = 0; r < 16; ++r) {
      float p = __expf(s[r] - mnew);
      s[r] = p;
      ls += p;
    }
    ls += __shfl_xor(ls, 32);
    lrun = lrun * sc_old + ls;
    mrun = mnew;
#pragma unroll
    for (int r = 0; r < 16; ++r) { oa0[r] *= sc_old; oa1[r] *= sc_old; }

    unsigned int w[8];
#pragma unroll
    for (int i = 0; i < 8; ++i) {
      float plo = s[2 * i], phi = s[2 * i + 1];
      unsigned int pk;
      asm("v_cvt_pk_bf16_f32 %0, %1, %2" : "=v"(pk) : "v"(plo), "v"(phi));
      w[i] = pk;
    }
#pragma unroll
    for (int m = 0; m < 2; ++m) {
      unsigned int u0 = w[4 * m + 0], u1 = w[4 * m + 1];
      unsigned int u2 = w[4 * m + 2], u3 = w[4 * m + 3];
      asm volatile("v_permlane32_swap_b32 %0, %1" : "+v"(u0), "+v"(u2));
      asm volatile("v_permlane32_swap_b32 %0, %1" : "+v"(u1), "+v"(u3));
      union { unsigned int u[4]; bf16x8 v; } bp;
      bp.u[0] = u0; bp.u[1] = u1; bp.u[2] = u2; bp.u[3] = u3;
      const int ck = ((kb * 4 + m * 2 + hi) ^ (nlo & 7)) * 8;
      bf16x8 av0 = *(const bf16x8*)(vbuf + (nlo) * 256 + ck);
      bf16x8 av1 = *(const bf16x8*)(vbuf + (32 + nlo) * 256 + ck);
      oa0 = __builtin_amdgcn_mfma_f32_32x32x16_bf16(av0, bp.v, oa0, 0, 0, 0);
      oa1 = __builtin_amdgcn_mfma_f32_32x32x16_bf16(av1, bp.v, oa1, 0, 0, 0);
    }
  }

  const float rinv = 1.f / lrun;
  short* ob = o + ((long long)b * N_ + n0 + nlo) * C_ + h * DH_;
#pragma unroll
  for (int a = 0; a < 4; ++a) {
    short4 p0, p1;
    p0.x = f2bf(oa0[4 * a + 0] * rinv); p0.y = f2bf(oa0[4 * a + 1] * rinv);
    p0.z = f2bf(oa0[4 * a + 2] * rinv); p0.w = f2bf(oa0[4 * a + 3] * rinv);
    p1.x = f2bf(oa1[4 * a + 0] * rinv); p1.y = f2bf(oa1[4 * a + 1] * rinv);
    p1.z = f2bf(oa1[4 * a + 2] * rinv); p1.w = f2bf(oa1[4 * a + 3] * rinv);
    *(short4*)(ob + a * 8 + hi * 4) = p0;
    *(short4*)(ob + 32 + a * 8 + hi * 4) = p1;
  }
}

extern "C" void kernel_launch(void* const* d_in, const int* in_sizes, int n_in,
                              void* d_out, int out_size, void* d_ws, size_t ws_size,
                              hipStream_t stream) {
  (void)in_sizes; (void)n_in; (void)out_size; (void)ws_size;
  const float* x      = (const float*)d_in[0];
  const float* gamma  = (const float*)d_in[1];
  const float* beta   = (const float*)d_in[2];
  const float* w_qkv  = (const float*)d_in[3];
  const float* b_qkv  = (const float*)d_in[4];
  const float* E      = (const float*)d_in[5];
  const float* F      = (const float*)d_in[6];
  const float* w_o    = (const float*)d_in[7];
  const float* b_o    = (const float*)d_in[8];
  const float* w_proj = (const float*)d_in[9];
  const float* b_proj = (const float*)d_in[10];
  float* out = (float*)d_out;

  char* ws = (char*)d_ws;
  short* xnc    = (short*)ws;  ws += 16777216LL;   // [16][512][1024] bf16
  short* xnT    = (short*)ws;  ws += 16777216LL;   // [16][1024][512] bf16 (later: attno)
  short* qbuf   = (short*)ws;  ws += 16777216LL;   // [16][1024][512] bf16
  short* xEF    = (short*)ws;  ws += 8388608LL;    // [16][512][512] bf16 (xE 0-255, xF 256-511)
  short* kpb    = (short*)ws;  ws += 4194304LL;    // [16][256][512] bf16
  short* vpb    = (short*)ws;  ws += 4194304LL;    // [16][512][256] bf16
  short* wqkv_b = (short*)ws;  ws += 1572864LL;    // [1536][512] bf16
  short* wproj_b= (short*)ws;  ws += 524288LL;     // [512][512] bf16
  short* woT_b  = (short*)ws;  ws += 524288LL;     // [512][512] bf16 (w_o^T)
  short* wcomb_b= (short*)ws;  ws += 524288LL;     // [512][512] bf16 (w_proj*w_o)
  short* etft   = (short*)ws;  ws += 1048576LL;    // [512][1024] bf16 (Et; Ft at +256 rows)
  float2* part  = (float2*)ws; ws += 8192LL;       // [1024]
  float* esum   = (float*)ws;  ws += 1024LL;       // [256]
  float* fsum   = (float*)ws;  ws += 1024LL;       // [256]
  float* b2     = (float*)ws;  ws += 2048LL;       // [512]
  short* attno  = xnT;                             // alias
  short* Et     = etft;
  short* Ft     = etft + 262144;

  // 1-2: GroupNorm
  gn_stats1<<<dim3(1024), dim3(256), 0, stream>>>(x, part);
  gn_apply<<<dim3(16, 8, 16), dim3(256), 0, stream>>>(x, gamma, beta, part, xnc, xnT);

  // 3: all weight prep
  prep_all<<<dim3(266), dim3(256), 0, stream>>>(
      w_qkv, w_proj, w_o, E, F, b_o, b_proj,
      wqkv_b, wproj_b, woT_b, Et, Ft, esum, fsum, b2);

  // 4: mega1 = { q, xEF, wcomb }
  GJob jq   = { xnT, wqkv_b, qbuf, b_qkv, nullptr, nullptr,
                1024, 512, 512, 524288LL, 0LL, 524288LL, 8, 4, 512, 2, 1, 0 };
  GJob jxef = { etft, xnc, xEF, nullptr, nullptr, nullptr,
                512, 512, 1024, 0LL, 524288LL, 262144LL, 4, 4, 256, 0, 1, 0 };
  GJob jwc  = { wproj_b, woT_b, wcomb_b, nullptr, nullptr, nullptr,
                512, 512, 512, 0LL, 0LL, 0LL, 4, 4, 16, 0, 1, 0 };
  gemm_multi<<<dim3(784), dim3(256), 0, stream>>>(jq, jxef, jwc, 3);

  // 5: mega2 = { kp, vp }
  GJob jkp  = { xEF, wqkv_b + 262144, kpb, esum, b_qkv + 512, nullptr,
                256, 512, 512, 262144LL, 0LL, 131072LL, 2, 4, 128, 3, 1, 0 };
  GJob jvp  = { wqkv_b + 524288, xEF + 131072, vpb, b_qkv + 1024, fsum, nullptr,
                512, 256, 512, 0LL, 262144LL, 131072LL, 4, 2, 128, 3, 1, 0 };
  gemm_multi<<<dim3(256), dim3(256), 0, stream>>>(jkp, jvp, jkp, 2);

  // 6: attention
  attn_fused32<<<dim3(4, 8, 16), dim3(512), 0, stream>>>(qbuf, kpb, vpb, attno);

  // 7: S5
  GJob js5  = { wcomb_b, attno, out, b2, nullptr, xnc,
                512, 1024, 512, 0LL, 524288LL, 524288LL, 4, 8, 512, 1, 0, 1 };
  gemm_multi<<<dim3(512), dim3(256), 0, stream>>>(js5, js5, js5, 1);
}

// Round 11
// 150.902 us; speedup vs baseline: 1.0756x; 1.0756x over previous
//
#include <hip/hip_runtime.h>
#include <hip/hip_bf16.h>

#define B_ 16
#define C_ 512
#define N_ 1024
#define KL 256
#define HEADS_ 8
#define DH_ 64

typedef __attribute__((ext_vector_type(8))) short bf16x8;
typedef __attribute__((ext_vector_type(4))) float f32x4;
typedef __attribute__((ext_vector_type(16))) float f32x16;

__device__ inline short f2bf(float f) {
  __hip_bfloat16 h = __float2bfloat16(f);
  return *reinterpret_cast<short*>(&h);
}

__device__ inline float bf2f(short s) {
  union { unsigned int u; float f; } c;
  c.u = ((unsigned int)(unsigned short)s) << 16;
  return c.f;
}

__device__ inline void gload16(const void* g, void* l) {
  __builtin_amdgcn_global_load_lds(
      (const __attribute__((address_space(1))) void*)g,
      (__attribute__((address_space(3))) void*)l, 16, 0, 0);
}

// ---------------- GroupNorm stats pass 1: 1024 blocks
__global__ __launch_bounds__(256) void gn_stats1(const float* __restrict__ x,
                                                 float2* __restrict__ part) {
  const int tid = threadIdx.x;
  const int lane = tid & 63, wid = tid >> 6;
  const float4* b4 = (const float4*)(x + (long long)blockIdx.x * 8192);
  float s = 0.f, sq = 0.f;
#pragma unroll
  for (int j = 0; j < 8; ++j) {
    float4 v = b4[tid + j * 256];
    s += v.x + v.y + v.z + v.w;
    sq += v.x * v.x + v.y * v.y + v.z * v.z + v.w * v.w;
  }
#pragma unroll
  for (int m = 1; m < 64; m <<= 1) {
    s += __shfl_xor(s, m);
    sq += __shfl_xor(sq, m);
  }
  __shared__ float red[8];
  if (lane == 0) { red[wid] = s; red[4 + wid] = sq; }
  __syncthreads();
  if (tid == 0)
    part[blockIdx.x] = make_float2(red[0] + red[1] + red[2] + red[3],
                                   red[4] + red[5] + red[6] + red[7]);
}

// ---------------- GroupNorm apply (stats finalize inlined per block)
__global__ __launch_bounds__(256) void gn_apply(
    const float* __restrict__ x, const float* __restrict__ gamma,
    const float* __restrict__ beta, const float2* __restrict__ part,
    short* __restrict__ xnc, short* __restrict__ xnT) {
  const int t = blockIdx.x, g = blockIdx.y, b = blockIdx.z;
  float s = 0.f, sq = 0.f;
#pragma unroll
  for (int j = 0; j < 8; ++j) {
    float2 p = part[(b * 8 + g) * 8 + j];
    s += p.x; sq += p.y;
  }
  const float mu = s * (1.f / 65536.f);
  const float var = sq * (1.f / 65536.f) - mu * mu;
  const float rs = rsqrtf(var + 1e-5f);

  __shared__ short tile[64 * 65];
#pragma unroll
  for (int i = 0; i < 4; ++i) {
    const int idx = threadIdx.x + i * 256;
    const int cl = idx >> 4;
    const int nl0 = (idx & 15) * 4;
    const int ch = g * 64 + cl;
    const long long gi = ((long long)(b * C_ + ch)) * N_ + t * 64 + nl0;
    const float4 v = *(const float4*)(x + gi);
    const float gm = gamma[ch], bt = beta[ch];
    short s0 = f2bf((v.x - mu) * rs * gm + bt);
    short s1 = f2bf((v.y - mu) * rs * gm + bt);
    short s2 = f2bf((v.z - mu) * rs * gm + bt);
    short s3 = f2bf((v.w - mu) * rs * gm + bt);
    short4 pk; pk.x = s0; pk.y = s1; pk.z = s2; pk.w = s3;
    *(short4*)(xnc + gi) = pk;
    tile[cl * 65 + nl0] = s0;
    tile[cl * 65 + nl0 + 1] = s1;
    tile[cl * 65 + nl0 + 2] = s2;
    tile[cl * 65 + nl0 + 3] = s3;
  }
  __syncthreads();

#pragma unroll
  for (int i = 0; i < 4; ++i) {
    const int idx = threadIdx.x + i * 256;
    const int cl0 = (idx & 15) * 4;
    const int nl = idx >> 4;
    short4 pk;
    pk.x = tile[(cl0 + 0) * 65 + nl];
    pk.y = tile[(cl0 + 1) * 65 + nl];
    pk.z = tile[(cl0 + 2) * 65 + nl];
    pk.w = tile[(cl0 + 3) * 65 + nl];
    *(short4*)(xnT + ((long long)b * N_ + t * 64 + nl) * C_ + g * 64 + cl0) = pk;
  }
}

// ---------------- ALL weight prep in ONE launch (266 blocks)
__global__ __launch_bounds__(256) void prep_all(
    const float* __restrict__ w_qkv, const float* __restrict__ w_proj,
    const float* __restrict__ w_o, const float* __restrict__ E,
    const float* __restrict__ F, const float* __restrict__ b_o,
    const float* __restrict__ b_proj,
    short* __restrict__ wqkv_b, short* __restrict__ wproj_b,
    short* __restrict__ woT_b, short* __restrict__ Et, short* __restrict__ Ft,
    float* __restrict__ esum, float* __restrict__ fsum, float* __restrict__ b2) {
  __shared__ float tl[64 * 65];
  int bid = blockIdx.x;
  const int tid = threadIdx.x;

  if (bid < 64) {  // dtype converts
    const float4* src;
    short4* dst;
    if (bid < 48) { src = (const float4*)w_qkv + bid * 4096; dst = (short4*)wqkv_b + bid * 4096; }
    else          { src = (const float4*)w_proj + (bid - 48) * 4096; dst = (short4*)wproj_b + (bid - 48) * 4096; }
#pragma unroll
    for (int i = 0; i < 16; ++i) {
      float4 v = src[tid + i * 256];
      short4 p; p.x = f2bf(v.x); p.y = f2bf(v.y); p.z = f2bf(v.z); p.w = f2bf(v.w);
      dst[tid + i * 256] = p;
    }
    return;
  }
  bid -= 64;
  if (bid < 192) {  // transposes: w_o (64), E (64), F (64)
    const float* src; short* dst; int sN, tr, tc;
    if (bid < 64) { src = w_o; dst = woT_b; sN = 512; tr = bid >> 3; tc = bid & 7; }
    else if (bid < 128) { src = E; dst = Et; sN = 256; tr = (bid - 64) & 15; tc = (bid - 64) >> 4; }
    else { src = F; dst = Ft; sN = 256; tr = (bid - 128) & 15; tc = (bid - 128) >> 4; }
    const int R = (sN == 512) ? 512 : 1024;
#pragma unroll 4
    for (int i = 0; i < 16; ++i) {
      const int idx = tid + i * 256;
      const int rl = idx >> 6, cl = idx & 63;
      tl[rl * 65 + cl] = src[(tr * 64 + rl) * sN + tc * 64 + cl];
    }
    __syncthreads();
#pragma unroll 4
    for (int i = 0; i < 16; ++i) {
      const int idx = tid + i * 256;
      const int cl = idx >> 6, rl = idx & 63;
      dst[(tc * 64 + cl) * R + tr * 64 + rl] = f2bf(tl[rl * 65 + cl]);
    }
    return;
  }
  bid -= 192;
  if (bid < 8) {  // colsum
    __shared__ float cs[4][64];
    const float* src = (bid < 4) ? E : F;
    float* dst = (bid < 4) ? esum : fsum;
    const int cb = (bid & 3) * 64;
    const int col = cb + (tid & 63), seg = tid >> 6;
    float s = 0.f;
    for (int n = seg * 256; n < seg * 256 + 256; ++n) s += src[n * 256 + col];
    cs[seg][tid & 63] = s;
    __syncthreads();
    if (tid < 64) dst[cb + tid] = cs[0][tid] + cs[1][tid] + cs[2][tid] + cs[3][tid];
    return;
  }
  bid -= 8;
  {  // b2
    const int o = bid * 256 + tid;
    float s = b_proj[o];
    for (int m = 0; m < 512; ++m) s += w_proj[o * 512 + m] * b_o[m];
    b2[o] = s;
  }
}

// ---------------- generic GEMM: C[M][Nn] = A (M x Kd) * Bt (Nn x Kd)^T
// TEMPLATED epilogue (r6-proven), SINGLE-buffered 32 KB LDS (3 blocks/CU —
// m132: 64 KB dbuf costs a blocks/CU and regressed), __syncthreads loop,
// bijective XCD chunk swizzle (nblk % 8 == 0 for all launches).
// BIAS_MODE: 0 none, 1 bias[row], 2 bias[col], 3 bias[row]*bias2[col].
template <int BIAS_MODE, bool OUT_BF16, bool RESID>
__global__ __launch_bounds__(256) void gemm_bt(
    const short* __restrict__ A, const short* __restrict__ Bt,
    void* __restrict__ Cout, const float* __restrict__ bias,
    const float* __restrict__ bias2, const short* __restrict__ resid,
    int M, int Nn, int Kd, long long sA, long long sB, long long sC) {
  const int gx = gridDim.x, gy = gridDim.y;
  const int nwg = gx * gy * gridDim.z;
  const int bid = blockIdx.x + gx * (blockIdx.y + gy * blockIdx.z);
  const int cpx = nwg >> 3;
  int w = (bid & 7) * cpx + (bid >> 3);
  const int mx = w % gx; w /= gx;
  const int ny = w % gy;
  const int bz = w / gy;

  const int m0 = mx * 128;
  const int n0 = ny * 128;
  const short* Ab = A + bz * sA;
  const short* Bb = Bt + bz * sB;
  const int tid = threadIdx.x;
  const int lane = tid & 63;
  const int wid = tid >> 6;
  const int wm = wid >> 1, wn = wid & 1;

  __shared__ __align__(16) short As[128 * 64];
  __shared__ __align__(16) short Bs[128 * 64];

  f32x4 acc[4][4] = {};

  for (int kt = 0; kt < Kd; kt += 64) {
#pragma unroll
    for (int r = 0; r < 4; ++r) {
      const int dbase = r * 4096 + wid * 1024;
      const int dbyte = dbase + (lane << 4);
      const int row = dbyte >> 7;
      const int chunk = ((dbyte >> 4) & 7) ^ (row & 7);
      gload16(Ab + (long long)(m0 + row) * Kd + kt + chunk * 8, (char*)As + dbase);
      gload16(Bb + (long long)(n0 + row) * Kd + kt + chunk * 8, (char*)Bs + dbase);
    }
    __syncthreads();
#pragma unroll
    for (int kk = 0; kk < 2; ++kk) {
      bf16x8 af[4], bfr[4];
#pragma unroll
      for (int mi = 0; mi < 4; ++mi) {
        int row = wm * 64 + mi * 16 + (lane & 15);
        int chunk = (kk * 4 + (lane >> 4)) ^ (row & 7);
        af[mi] = *(const bf16x8*)(As + row * 64 + chunk * 8);
      }
#pragma unroll
      for (int ni = 0; ni < 4; ++ni) {
        int row = wn * 64 + ni * 16 + (lane & 15);
        int chunk = (kk * 4 + (lane >> 4)) ^ (row & 7);
        bfr[ni] = *(const bf16x8*)(Bs + row * 64 + chunk * 8);
      }
#pragma unroll
      for (int mi = 0; mi < 4; ++mi)
#pragma unroll
        for (int ni = 0; ni < 4; ++ni)
          acc[mi][ni] = __builtin_amdgcn_mfma_f32_16x16x32_bf16(af[mi], bfr[ni], acc[mi][ni], 0, 0, 0);
    }
    __syncthreads();
  }

#pragma unroll
  for (int mi = 0; mi < 4; ++mi) {
#pragma unroll
    for (int ni = 0; ni < 4; ++ni) {
      const int row = m0 + wm * 64 + mi * 16 + ((lane >> 4) << 2);
      const int col = n0 + wn * 64 + ni * 16 + (lane & 15);
      f32x4 v = acc[mi][ni];
#pragma unroll
      for (int j = 0; j < 4; ++j) {
        float val = v[j];
        if (BIAS_MODE == 1) val += bias[row + j];
        if (BIAS_MODE == 2) val += bias[col];
        if (BIAS_MODE == 3) val += bias[row + j] * bias2[col];
        const long long ci = (long long)bz * sC + (long long)(row + j) * Nn + col;
        if (RESID) val += bf2f(resid[ci]);
        if (OUT_BF16) ((short*)Cout)[ci] = f2bf(val);
        else ((float*)Cout)[ci] = val;
      }
    }
  }
}

// ---------------- fused Linformer attention, 32x32 swapped-QK, in-register softmax
__global__ __launch_bounds__(512, 4) void attn_fused32(
    const short* __restrict__ q, const short* __restrict__ kp,
    const short* __restrict__ vp, short* __restrict__ o) {
  const int qt = blockIdx.x;
  const int h = blockIdx.y;
  const int b = blockIdx.z;
  const int tid = threadIdx.x;
  const int lane = tid & 63;
  const int wid = tid >> 6;
  const int nlo = lane & 31;
  const int hi = lane >> 5;

  __shared__ __align__(16) short kbuf[256 * 64];
  __shared__ __align__(16) short vbuf[64 * 256];

  {
    const short* base = kp + (long long)b * (KL * C_) + h * DH_;
#pragma unroll
    for (int i = 0; i < 4; ++i) {
      const int dbyte = (i * 512 + tid) * 16;
      const int row = dbyte >> 7;
      const int chunk = ((dbyte >> 4) & 7) ^ (row & 7);
      gload16(base + row * C_ + chunk * 8, (char*)kbuf + dbyte);
    }
  }
  {
    const short* base = vp + ((long long)b * C_ + h * DH_) * KL;
#pragma unroll
    for (int i = 0; i < 4; ++i) {
      const int dbyte = (i * 512 + tid) * 16;
      const int row = dbyte >> 9;
      const int chunk = ((dbyte >> 4) & 31) ^ (row & 7);
      gload16(base + row * KL + chunk * 8, (char*)vbuf + dbyte);
    }
  }

  const int n0 = qt * 256 + wid * 32;
  bf16x8 bq[4];
  {
    const short* qb = q + ((long long)b * N_ + n0 + nlo) * C_ + h * DH_ + hi * 8;
#pragma unroll
    for (int dk = 0; dk < 4; ++dk) bq[dk] = *(const bf16x8*)(qb + dk * 16);
  }
  __syncthreads();

  f32x16 oa0, oa1;
#pragma unroll
  for (int r = 0; r < 16; ++r) { oa0[r] = 0.f; oa1[r] = 0.f; }
  float mrun = -1e30f, lrun = 0.f;

#pragma unroll
  for (int kb = 0; kb < 8; ++kb) {
    f32x16 s;
#pragma unroll
    for (int r = 0; r < 16; ++r) s[r] = 0.f;
#pragma unroll
    for (int dk = 0; dk < 4; ++dk) {
      const int row = kb * 32 + nlo;
      bf16x8 ak = *(const bf16x8*)(kbuf + row * 64 + (((dk * 2 + hi) ^ (nlo & 7)) * 8));
      s = __builtin_amdgcn_mfma_f32_32x32x16_bf16(ak, bq[dk], s, 0, 0, 0);
    }
    float lm = -1e30f;
#pragma unroll
    for (int r = 0; r < 16; ++r) { s[r] *= 0.125f; lm = fmaxf(lm, s[r]); }
    lm = fmaxf(lm, __shfl_xor(lm, 32));
    const float mnew = fmaxf(mrun, lm);
    const float sc_old = __expf(mrun - mnew);
    float ls = 0.f;
#pragma unroll
    for (int r = 0; r < 16; ++r) {
      float p = __expf(s[r] - mnew);
      s[r] = p;
      ls += p;
    }
    ls += __shfl_xor(ls, 32);
    lrun = lrun * sc_old + ls;
    mrun = mnew;
#pragma unroll
    for (int r = 0; r < 16; ++r) { oa0[r] *= sc_old; oa1[r] *= sc_old; }

    unsigned int w[8];
#pragma unroll
    for (int i = 0; i < 8; ++i) {
      float plo = s[2 * i], phi = s[2 * i + 1];
      unsigned int pk;
      asm("v_cvt_pk_bf16_f32 %0, %1, %2" : "=v"(pk) : "v"(plo), "v"(phi));
      w[i] = pk;
    }
#pragma unroll
    for (int m = 0; m < 2; ++m) {
      unsigned int u0 = w[4 * m + 0], u1 = w[4 * m + 1];
      unsigned int u2 = w[4 * m + 2], u3 = w[4 * m + 3];
      asm volatile("v_permlane32_swap_b32 %0, %1" : "+v"(u0), "+v"(u2));
      asm volatile("v_permlane32_swap_b32 %0, %1" : "+v"(u1), "+v"(u3));
      union { unsigned int u[4]; bf16x8 v; } bp;
      bp.u[0] = u0; bp.u[1] = u1; bp.u[2] = u2; bp.u[3] = u3;
      const int ck = ((kb * 4 + m * 2 + hi) ^ (nlo & 7)) * 8;
      bf16x8 av0 = *(const bf16x8*)(vbuf + (nlo) * 256 + ck);
      bf16x8 av1 = *(const bf16x8*)(vbuf + (32 + nlo) * 256 + ck);
      oa0 = __builtin_amdgcn_mfma_f32_32x32x16_bf16(av0, bp.v, oa0, 0, 0, 0);
      oa1 = __builtin_amdgcn_mfma_f32_32x32x16_bf16(av1, bp.v, oa1, 0, 0, 0);
    }
  }

  const float rinv = 1.f / lrun;
  short* ob = o + ((long long)b * N_ + n0 + nlo) * C_ + h * DH_;
#pragma unroll
  for (int a = 0; a < 4; ++a) {
    short4 p0, p1;
    p0.x = f2bf(oa0[4 * a + 0] * rinv); p0.y = f2bf(oa0[4 * a + 1] * rinv);
    p0.z = f2bf(oa0[4 * a + 2] * rinv); p0.w = f2bf(oa0[4 * a + 3] * rinv);
    p1.x = f2bf(oa1[4 * a + 0] * rinv); p1.y = f2bf(oa1[4 * a + 1] * rinv);
    p1.z = f2bf(oa1[4 * a + 2] * rinv); p1.w = f2bf(oa1[4 * a + 3] * rinv);
    *(short4*)(ob + a * 8 + hi * 4) = p0;
    *(short4*)(ob + 32 + a * 8 + hi * 4) = p1;
  }
}

extern "C" void kernel_launch(void* const* d_in, const int* in_sizes, int n_in,
                              void* d_out, int out_size, void* d_ws, size_t ws_size,
                              hipStream_t stream) {
  (void)in_sizes; (void)n_in; (void)out_size; (void)ws_size;
  const float* x      = (const float*)d_in[0];
  const float* gamma  = (const float*)d_in[1];
  const float* beta   = (const float*)d_in[2];
  const float* w_qkv  = (const float*)d_in[3];
  const float* b_qkv  = (const float*)d_in[4];
  const float* E      = (const float*)d_in[5];
  const float* F      = (const float*)d_in[6];
  const float* w_o    = (const float*)d_in[7];
  const float* b_o    = (const float*)d_in[8];
  const float* w_proj = (const float*)d_in[9];
  const float* b_proj = (const float*)d_in[10];
  float* out = (float*)d_out;

  char* ws = (char*)d_ws;
  short* xnc    = (short*)ws;  ws += 16777216LL;   // [16][512][1024] bf16
  short* xnT    = (short*)ws;  ws += 16777216LL;   // [16][1024][512] bf16 (later: attno)
  short* qbuf   = (short*)ws;  ws += 16777216LL;   // [16][1024][512] bf16
  short* xEF    = (short*)ws;  ws += 8388608LL;    // [16][512][512] bf16 (xE 0-255, xF 256-511)
  short* kpb    = (short*)ws;  ws += 4194304LL;    // [16][256][512] bf16
  short* vpb    = (short*)ws;  ws += 4194304LL;    // [16][512][256] bf16
  short* wqkv_b = (short*)ws;  ws += 1572864LL;    // [1536][512] bf16
  short* wproj_b= (short*)ws;  ws += 524288LL;     // [512][512] bf16
  short* woT_b  = (short*)ws;  ws += 524288LL;     // [512][512] bf16 (w_o^T)
  short* wcomb_b= (short*)ws;  ws += 524288LL;     // [512][512] bf16 (w_proj*w_o)
  short* etft   = (short*)ws;  ws += 1048576LL;    // [512][1024] bf16 (Et; Ft at +256 rows)
  float2* part  = (float2*)ws; ws += 8192LL;       // [1024]
  float* esum   = (float*)ws;  ws += 1024LL;       // [256]
  float* fsum   = (float*)ws;  ws += 1024LL;       // [256]
  float* b2     = (float*)ws;  ws += 2048LL;       // [512]
  short* attno  = xnT;                             // alias
  short* Et     = etft;
  short* Ft     = etft + 262144;

  // 1-2: GroupNorm
  gn_stats1<<<dim3(1024), dim3(256), 0, stream>>>(x, part);
  gn_apply<<<dim3(16, 8, 16), dim3(256), 0, stream>>>(x, gamma, beta, part, xnc, xnT);

  // 3: all weight prep
  prep_all<<<dim3(266), dim3(256), 0, stream>>>(
      w_qkv, w_proj, w_o, E, F, b_o, b_proj,
      wqkv_b, wproj_b, woT_b, Et, Ft, esum, fsum, b2);

  // 4: wcomb = w_proj * w_o  (tiny; launch first among GEMMs)
  gemm_bt<0, true, false><<<dim3(4, 4, 1), dim3(256), 0, stream>>>(
      wproj_b, woT_b, wcomb_b, nullptr, nullptr, nullptr,
      512, 512, 512, 0LL, 0LL, 0LL);

  // 5: q[b][n][o] = xnT[b] * w_q^T + b_q[col]
  gemm_bt<2, true, false><<<dim3(8, 4, 16), dim3(256), 0, stream>>>(
      xnT, wqkv_b, qbuf, b_qkv, nullptr, nullptr,
      1024, 512, 512, 524288LL, 0LL, 524288LL);

  // 6: xEF[b] = [Et;Ft] (512x1024) * xnc[b]^T -> [k(512)][c(512)]
  gemm_bt<0, true, false><<<dim3(4, 4, 16), dim3(256), 0, stream>>>(
      etft, xnc, xEF, nullptr, nullptr, nullptr,
      512, 512, 1024, 0LL, 524288LL, 262144LL);

  // 7: kp[b][k][c'] = xE[b] (256x512) * w_k^T + esum[k]*b_k[c']
  gemm_bt<3, true, false><<<dim3(2, 4, 16), dim3(256), 0, stream>>>(
      xEF, wqkv_b + 262144, kpb, esum, b_qkv + 512, nullptr,
      256, 512, 512, 262144LL, 0LL, 131072LL);

  // 8: vp[b][c'][k] = w_v (512x512) * xF[b]^T + b_v[c']*fsum[k]
  gemm_bt<3, true, false><<<dim3(4, 2, 16), dim3(256), 0, stream>>>(
      wqkv_b + 524288, xEF + 131072, vpb, b_qkv + 1024, fsum, nullptr,
      512, 256, 512, 0LL, 262144LL, 131072LL);

  // 9: attention
  attn_fused32<<<dim3(4, 8, 16), dim3(512), 0, stream>>>(qbuf, kpb, vpb, attno);

  // 10: S5: out[b][o][n] = wcomb * attno[b]^T + b2[row] + xnc
  gemm_bt<1, false, true><<<dim3(4, 8, 16), dim3(256), 0, stream>>>(
      wcomb_b, attno, out, b2, nullptr, xnc,
      512, 1024, 512, 0LL, 524288LL, 524288LL);
}

// Round 13
// 138.170 us; speedup vs baseline: 1.1747x; 1.0921x over previous
//
#include <hip/hip_runtime.h>
#include <hip/hip_bf16.h>

#define B_ 16
#define C_ 512
#define N_ 1024
#define KL 256
#define HEADS_ 8
#define DH_ 64

typedef __attribute__((ext_vector_type(8))) short bf16x8;
typedef __attribute__((ext_vector_type(4))) float f32x4;
typedef __attribute__((ext_vector_type(16))) float f32x16;

__device__ inline short f2bf(float f) {
  __hip_bfloat16 h = __float2bfloat16(f);
  return *reinterpret_cast<short*>(&h);
}

__device__ inline float bf2f(short s) {
  union { unsigned int u; float f; } c;
  c.u = ((unsigned int)(unsigned short)s) << 16;
  return c.f;
}

__device__ inline void gload16(const void* g, void* l) {
  __builtin_amdgcn_global_load_lds(
      (const __attribute__((address_space(1))) void*)g,
      (__attribute__((address_space(3))) void*)l, 16, 0, 0);
}

// ---------------- merged: GN stats pass1 (blocks 0..1023) + weight prep (1024..1289)
__global__ __launch_bounds__(256) void stats_prep(
    const float* __restrict__ x, float2* __restrict__ part,
    const float* __restrict__ w_qkv, const float* __restrict__ w_proj,
    const float* __restrict__ w_o, const float* __restrict__ E,
    const float* __restrict__ F, const float* __restrict__ b_o,
    const float* __restrict__ b_proj,
    short* __restrict__ wqkv_b, short* __restrict__ wproj_b,
    short* __restrict__ woT_b, short* __restrict__ Et, short* __restrict__ Ft,
    float* __restrict__ esum, float* __restrict__ fsum, float* __restrict__ b2) {
  __shared__ float tl[64 * 65];
  __shared__ float red[8];
  __shared__ float cs[4][64];
  int bid = blockIdx.x;
  const int tid = threadIdx.x;

  if (bid < 1024) {  // GN stats slice
    const int lane = tid & 63, wid = tid >> 6;
    const float4* b4 = (const float4*)(x + (long long)bid * 8192);
    float s = 0.f, sq = 0.f;
#pragma unroll
    for (int j = 0; j < 8; ++j) {
      float4 v = b4[tid + j * 256];
      s += v.x + v.y + v.z + v.w;
      sq += v.x * v.x + v.y * v.y + v.z * v.z + v.w * v.w;
    }
#pragma unroll
    for (int m = 1; m < 64; m <<= 1) {
      s += __shfl_xor(s, m);
      sq += __shfl_xor(sq, m);
    }
    if (lane == 0) { red[wid] = s; red[4 + wid] = sq; }
    __syncthreads();
    if (tid == 0)
      part[bid] = make_float2(red[0] + red[1] + red[2] + red[3],
                              red[4] + red[5] + red[6] + red[7]);
    return;
  }
  bid -= 1024;

  if (bid < 64) {  // dtype converts
    const float4* src;
    short4* dst;
    if (bid < 48) { src = (const float4*)w_qkv + bid * 4096; dst = (short4*)wqkv_b + bid * 4096; }
    else          { src = (const float4*)w_proj + (bid - 48) * 4096; dst = (short4*)wproj_b + (bid - 48) * 4096; }
#pragma unroll
    for (int i = 0; i < 16; ++i) {
      float4 v = src[tid + i * 256];
      short4 p; p.x = f2bf(v.x); p.y = f2bf(v.y); p.z = f2bf(v.z); p.w = f2bf(v.w);
      dst[tid + i * 256] = p;
    }
    return;
  }
  bid -= 64;
  if (bid < 192) {  // transposes: w_o (64), E (64), F (64)
    const float* src; short* dst; int sN, tr, tc;
    if (bid < 64) { src = w_o; dst = woT_b; sN = 512; tr = bid >> 3; tc = bid & 7; }
    else if (bid < 128) { src = E; dst = Et; sN = 256; tr = (bid - 64) & 15; tc = (bid - 64) >> 4; }
    else { src = F; dst = Ft; sN = 256; tr = (bid - 128) & 15; tc = (bid - 128) >> 4; }
    const int R = (sN == 512) ? 512 : 1024;
#pragma unroll 4
    for (int i = 0; i < 16; ++i) {
      const int idx = tid + i * 256;
      const int rl = idx >> 6, cl = idx & 63;
      tl[rl * 65 + cl] = src[(tr * 64 + rl) * sN + tc * 64 + cl];
    }
    __syncthreads();
#pragma unroll 4
    for (int i = 0; i < 16; ++i) {
      const int idx = tid + i * 256;
      const int cl = idx >> 6, rl = idx & 63;
      dst[(tc * 64 + cl) * R + tr * 64 + rl] = f2bf(tl[rl * 65 + cl]);
    }
    return;
  }
  bid -= 192;
  if (bid < 8) {  // colsum
    const float* src = (bid < 4) ? E : F;
    float* dst = (bid < 4) ? esum : fsum;
    const int cb = (bid & 3) * 64;
    const int col = cb + (tid & 63), seg = tid >> 6;
    float s = 0.f;
    for (int n = seg * 256; n < seg * 256 + 256; ++n) s += src[n * 256 + col];
    cs[seg][tid & 63] = s;
    __syncthreads();
    if (tid < 64) dst[cb + tid] = cs[0][tid] + cs[1][tid] + cs[2][tid] + cs[3][tid];
    return;
  }
  bid -= 8;
  {  // b2
    const int o = bid * 256 + tid;
    float s = b_proj[o];
    for (int m = 0; m < 512; ++m) s += w_proj[o * 512 + m] * b_o[m];
    b2[o] = s;
  }
}

// ---------------- GroupNorm apply (stats finalize inlined per block)
__global__ __launch_bounds__(256) void gn_apply(
    const float* __restrict__ x, const float* __restrict__ gamma,
    const float* __restrict__ beta, const float2* __restrict__ part,
    short* __restrict__ xnc, short* __restrict__ xnT) {
  const int t = blockIdx.x, g = blockIdx.y, b = blockIdx.z;
  float s = 0.f, sq = 0.f;
#pragma unroll
  for (int j = 0; j < 8; ++j) {
    float2 p = part[(b * 8 + g) * 8 + j];
    s += p.x; sq += p.y;
  }
  const float mu = s * (1.f / 65536.f);
  const float var = sq * (1.f / 65536.f) - mu * mu;
  const float rs = rsqrtf(var + 1e-5f);

  __shared__ short tile[64 * 65];
#pragma unroll
  for (int i = 0; i < 4; ++i) {
    const int idx = threadIdx.x + i * 256;
    const int cl = idx >> 4;
    const int nl0 = (idx & 15) * 4;
    const int ch = g * 64 + cl;
    const long long gi = ((long long)(b * C_ + ch)) * N_ + t * 64 + nl0;
    const float4 v = *(const float4*)(x + gi);
    const float gm = gamma[ch], bt = beta[ch];
    short s0 = f2bf((v.x - mu) * rs * gm + bt);
    short s1 = f2bf((v.y - mu) * rs * gm + bt);
    short s2 = f2bf((v.z - mu) * rs * gm + bt);
    short s3 = f2bf((v.w - mu) * rs * gm + bt);
    short4 pk; pk.x = s0; pk.y = s1; pk.z = s2; pk.w = s3;
    *(short4*)(xnc + gi) = pk;
    tile[cl * 65 + nl0] = s0;
    tile[cl * 65 + nl0 + 1] = s1;
    tile[cl * 65 + nl0 + 2] = s2;
    tile[cl * 65 + nl0 + 3] = s3;
  }
  __syncthreads();

#pragma unroll
  for (int i = 0; i < 4; ++i) {
    const int idx = threadIdx.x + i * 256;
    const int cl0 = (idx & 15) * 4;
    const int nl = idx >> 4;
    short4 pk;
    pk.x = tile[(cl0 + 0) * 65 + nl];
    pk.y = tile[(cl0 + 1) * 65 + nl];
    pk.z = tile[(cl0 + 2) * 65 + nl];
    pk.w = tile[(cl0 + 3) * 65 + nl];
    *(short4*)(xnT + ((long long)b * N_ + t * 64 + nl) * C_ + g * 64 + cl0) = pk;
  }
}

// ---------------- generic GEMM: C[M][Nn] = A (M x Kd) * Bt (Nn x Kd)^T
// 128x64 tile (BN=64): 24 KB LDS -> higher blocks/CU; grids 2-4x larger than the
// 128x128 version — attacks the grid-limited occupancy (r4: 18% occ, 1.5 blk/CU).
// Single-buffered, __syncthreads loop (r11-proven), bijective XCD chunk swizzle.
// BIAS_MODE: 0 none, 1 bias[row], 2 bias[col], 3 bias[row]*bias2[col].
template <int BIAS_MODE, bool OUT_BF16, bool RESID>
__global__ __launch_bounds__(256) void gemm_bt(
    const short* __restrict__ A, const short* __restrict__ Bt,
    void* __restrict__ Cout, const float* __restrict__ bias,
    const float* __restrict__ bias2, const short* __restrict__ resid,
    int M, int Nn, int Kd, long long sA, long long sB, long long sC) {
  const int gx = gridDim.x, gy = gridDim.y;
  const int nwg = gx * gy * gridDim.z;
  const int bid = blockIdx.x + gx * (blockIdx.y + gy * blockIdx.z);
  const int cpx = nwg >> 3;
  int w = (bid & 7) * cpx + (bid >> 3);
  const int mx = w % gx; w /= gx;
  const int ny = w % gy;
  const int bz = w / gy;

  const int m0 = mx * 128;
  const int n0 = ny * 64;
  const short* Ab = A + bz * sA;
  const short* Bb = Bt + bz * sB;
  const int tid = threadIdx.x;
  const int lane = tid & 63;
  const int wid = tid >> 6;
  const int wm = wid >> 1, wn = wid & 1;

  __shared__ __align__(16) short As[128 * 64];  // 16 KB
  __shared__ __align__(16) short Bs[64 * 64];   // 8 KB

  f32x4 acc[4][2] = {};

  for (int kt = 0; kt < Kd; kt += 64) {
#pragma unroll
    for (int r = 0; r < 4; ++r) {
      const int dbase = r * 4096 + wid * 1024;
      const int dbyte = dbase + (lane << 4);
      const int row = dbyte >> 7;
      const int chunk = ((dbyte >> 4) & 7) ^ (row & 7);
      gload16(Ab + (long long)(m0 + row) * Kd + kt + chunk * 8, (char*)As + dbase);
    }
#pragma unroll
    for (int r = 0; r < 2; ++r) {
      const int dbase = r * 4096 + wid * 1024;
      const int dbyte = dbase + (lane << 4);
      const int row = dbyte >> 7;
      const int chunk = ((dbyte >> 4) & 7) ^ (row & 7);
      gload16(Bb + (long long)(n0 + row) * Kd + kt + chunk * 8, (char*)Bs + dbase);
    }
    __syncthreads();
#pragma unroll
    for (int kk = 0; kk < 2; ++kk) {
      bf16x8 af[4], bfr[2];
#pragma unroll
      for (int mi = 0; mi < 4; ++mi) {
        int row = wm * 64 + mi * 16 + (lane & 15);
        int chunk = (kk * 4 + (lane >> 4)) ^ (row & 7);
        af[mi] = *(const bf16x8*)(As + row * 64 + chunk * 8);
      }
#pragma unroll
      for (int ni = 0; ni < 2; ++ni) {
        int row = wn * 32 + ni * 16 + (lane & 15);
        int chunk = (kk * 4 + (lane >> 4)) ^ (row & 7);
        bfr[ni] = *(const bf16x8*)(Bs + row * 64 + chunk * 8);
      }
#pragma unroll
      for (int mi = 0; mi < 4; ++mi)
#pragma unroll
        for (int ni = 0; ni < 2; ++ni)
          acc[mi][ni] = __builtin_amdgcn_mfma_f32_16x16x32_bf16(af[mi], bfr[ni], acc[mi][ni], 0, 0, 0);
    }
    __syncthreads();
  }

#pragma unroll
  for (int mi = 0; mi < 4; ++mi) {
#pragma unroll
    for (int ni = 0; ni < 2; ++ni) {
      const int row = m0 + wm * 64 + mi * 16 + ((lane >> 4) << 2);
      const int col = n0 + wn * 32 + ni * 16 + (lane & 15);
      f32x4 v = acc[mi][ni];
#pragma unroll
      for (int j = 0; j < 4; ++j) {
        float val = v[j];
        if (BIAS_MODE == 1) val += bias[row + j];
        if (BIAS_MODE == 2) val += bias[col];
        if (BIAS_MODE == 3) val += bias[row + j] * bias2[col];
        const long long ci = (long long)bz * sC + (long long)(row + j) * Nn + col;
        if (RESID) val += bf2f(resid[ci]);
        if (OUT_BF16) ((short*)Cout)[ci] = f2bf(val);
        else ((float*)Cout)[ci] = val;
      }
    }
  }
}

// ---------------- fused Linformer attention, 32x32 swapped-QK, in-register softmax
__global__ __launch_bounds__(512, 4) void attn_fused32(
    const short* __restrict__ q, const short* __restrict__ kp,
    const short* __restrict__ vp, short* __restrict__ o) {
  const int qt = blockIdx.x;
  const int h = blockIdx.y;
  const int b = blockIdx.z;
  const int tid = threadIdx.x;
  const int lane = tid & 63;
  const int wid = tid >> 6;
  const int nlo = lane & 31;
  const int hi = lane >> 5;

  __shared__ __align__(16) short kbuf[256 * 64];
  __shared__ __align__(16) short vbuf[64 * 256];

  {
    const short* base = kp + (long long)b * (KL * C_) + h * DH_;
#pragma unroll
    for (int i = 0; i < 4; ++i) {
      const int dbyte = (i * 512 + tid) * 16;
      const int row = dbyte >> 7;
      const int chunk = ((dbyte >> 4) & 7) ^ (row & 7);
      gload16(base + row * C_ + chunk * 8, (char*)kbuf + dbyte);
    }
  }
  {
    const short* base = vp + ((long long)b * C_ + h * DH_) * KL;
#pragma unroll
    for (int i = 0; i < 4; ++i) {
      const int dbyte = (i * 512 + tid) * 16;
      const int row = dbyte >> 9;
      const int chunk = ((dbyte >> 4) & 31) ^ (row & 7);
      gload16(base + row * KL + chunk * 8, (char*)vbuf + dbyte);
    }
  }

  const int n0 = qt * 256 + wid * 32;
  bf16x8 bq[4];
  {
    const short* qb = q + ((long long)b * N_ + n0 + nlo) * C_ + h * DH_ + hi * 8;
#pragma unroll
    for (int dk = 0; dk < 4; ++dk) bq[dk] = *(const bf16x8*)(qb + dk * 16);
  }
  __syncthreads();

  f32x16 oa0, oa1;
#pragma unroll
  for (int r = 0; r < 16; ++r) { oa0[r] = 0.f; oa1[r] = 0.f; }
  float mrun = -1e30f, lrun = 0.f;

#pragma unroll
  for (int kb = 0; kb < 8; ++kb) {
    f32x16 s;
#pragma unroll
    for (int r = 0; r < 16; ++r) s[r] = 0.f;
#pragma unroll
    for (int dk = 0; dk < 4; ++dk) {
      const int row = kb * 32 + nlo;
      bf16x8 ak = *(const bf16x8*)(kbuf + row * 64 + (((dk * 2 + hi) ^ (nlo & 7)) * 8));
      s = __builtin_amdgcn_mfma_f32_32x32x16_bf16(ak, bq[dk], s, 0, 0, 0);
    }
    float lm = -1e30f;
#pragma unroll
    for (int r = 0; r < 16; ++r) { s[r] *= 0.125f; lm = fmaxf(lm, s[r]); }
    lm = fmaxf(lm, __shfl_xor(lm, 32));
    const float mnew = fmaxf(mrun, lm);
    const float sc_old = __expf(mrun - mnew);
    float ls = 0.f;
#pragma unroll
    for (int r = 0; r < 16; ++r) {
      float p = __expf(s[r] - mnew);
      s[r] = p;
      ls += p;
    }
    ls += __shfl_xor(ls, 32);
    lrun = lrun * sc_old + ls;
    mrun = mnew;
#pragma unroll
    for (int r = 0; r < 16; ++r) { oa0[r] *= sc_old; oa1[r] *= sc_old; }

    unsigned int w[8];
#pragma unroll
    for (int i = 0; i < 8; ++i) {
      float plo = s[2 * i], phi = s[2 * i + 1];
      unsigned int pk;
      asm("v_cvt_pk_bf16_f32 %0, %1, %2" : "=v"(pk) : "v"(plo), "v"(phi));
      w[i] = pk;
    }
#pragma unroll
    for (int m = 0; m < 2; ++m) {
      unsigned int u0 = w[4 * m + 0], u1 = w[4 * m + 1];
      unsigned int u2 = w[4 * m + 2], u3 = w[4 * m + 3];
      asm volatile("v_permlane32_swap_b32 %0, %1" : "+v"(u0), "+v"(u2));
      asm volatile("v_permlane32_swap_b32 %0, %1" : "+v"(u1), "+v"(u3));
      union { unsigned int u[4]; bf16x8 v; } bp;
      bp.u[0] = u0; bp.u[1] = u1; bp.u[2] = u2; bp.u[3] = u3;
      const int ck = ((kb * 4 + m * 2 + hi) ^ (nlo & 7)) * 8;
      bf16x8 av0 = *(const bf16x8*)(vbuf + (nlo) * 256 + ck);
      bf16x8 av1 = *(const bf16x8*)(vbuf + (32 + nlo) * 256 + ck);
      oa0 = __builtin_amdgcn_mfma_f32_32x32x16_bf16(av0, bp.v, oa0, 0, 0, 0);
      oa1 = __builtin_amdgcn_mfma_f32_32x32x16_bf16(av1, bp.v, oa1, 0, 0, 0);
    }
  }

  const float rinv = 1.f / lrun;
  short* ob = o + ((long long)b * N_ + n0 + nlo) * C_ + h * DH_;
#pragma unroll
  for (int a = 0; a < 4; ++a) {
    short4 p0, p1;
    p0.x = f2bf(oa0[4 * a + 0] * rinv); p0.y = f2bf(oa0[4 * a + 1] * rinv);
    p0.z = f2bf(oa0[4 * a + 2] * rinv); p0.w = f2bf(oa0[4 * a + 3] * rinv);
    p1.x = f2bf(oa1[4 * a + 0] * rinv); p1.y = f2bf(oa1[4 * a + 1] * rinv);
    p1.z = f2bf(oa1[4 * a + 2] * rinv); p1.w = f2bf(oa1[4 * a + 3] * rinv);
    *(short4*)(ob + a * 8 + hi * 4) = p0;
    *(short4*)(ob + 32 + a * 8 + hi * 4) = p1;
  }
}

extern "C" void kernel_launch(void* const* d_in, const int* in_sizes, int n_in,
                              void* d_out, int out_size, void* d_ws, size_t ws_size,
                              hipStream_t stream) {
  (void)in_sizes; (void)n_in; (void)out_size; (void)ws_size;
  const float* x      = (const float*)d_in[0];
  const float* gamma  = (const float*)d_in[1];
  const float* beta   = (const float*)d_in[2];
  const float* w_qkv  = (const float*)d_in[3];
  const float* b_qkv  = (const float*)d_in[4];
  const float* E      = (const float*)d_in[5];
  const float* F      = (const float*)d_in[6];
  const float* w_o    = (const float*)d_in[7];
  const float* b_o    = (const float*)d_in[8];
  const float* w_proj = (const float*)d_in[9];
  const float* b_proj = (const float*)d_in[10];
  float* out = (float*)d_out;

  char* ws = (char*)d_ws;
  short* xnc    = (short*)ws;  ws += 16777216LL;   // [16][512][1024] bf16
  short* xnT    = (short*)ws;  ws += 16777216LL;   // [16][1024][512] bf16 (later: attno)
  short* qbuf   = (short*)ws;  ws += 16777216LL;   // [16][1024][512] bf16
  short* xEF    = (short*)ws;  ws += 8388608LL;    // [16][512][512] bf16 (xE 0-255, xF 256-511)
  short* kpb    = (short*)ws;  ws += 4194304LL;    // [16][256][512] bf16
  short* vpb    = (short*)ws;  ws += 4194304LL;    // [16][512][256] bf16
  short* wqkv_b = (short*)ws;  ws += 1572864LL;    // [1536][512] bf16
  short* wproj_b= (short*)ws;  ws += 524288LL;     // [512][512] bf16
  short* woT_b  = (short*)ws;  ws += 524288LL;     // [512][512] bf16 (w_o^T)
  short* wcomb_b= (short*)ws;  ws += 524288LL;     // [512][512] bf16 (w_proj*w_o)
  short* etft   = (short*)ws;  ws += 1048576LL;    // [512][1024] bf16 (Et; Ft at +256 rows)
  float2* part  = (float2*)ws; ws += 8192LL;       // [1024]
  float* esum   = (float*)ws;  ws += 1024LL;       // [256]
  float* fsum   = (float*)ws;  ws += 1024LL;       // [256]
  float* b2     = (float*)ws;  ws += 2048LL;       // [512]
  short* attno  = xnT;                             // alias
  short* Et     = etft;
  short* Ft     = etft + 262144;

  // 1: GN stats + ALL weight prep (merged, independent works)
  stats_prep<<<dim3(1290), dim3(256), 0, stream>>>(
      x, part, w_qkv, w_proj, w_o, E, F, b_o, b_proj,
      wqkv_b, wproj_b, woT_b, Et, Ft, esum, fsum, b2);

  // 2: GN apply
  gn_apply<<<dim3(16, 8, 16), dim3(256), 0, stream>>>(x, gamma, beta, part, xnc, xnT);

  // 3: wcomb = w_proj * w_o
  gemm_bt<0, true, false><<<dim3(4, 8, 1), dim3(256), 0, stream>>>(
      wproj_b, woT_b, wcomb_b, nullptr, nullptr, nullptr,
      512, 512, 512, 0LL, 0LL, 0LL);

  // 4: q[b][n][o] = xnT[b] * w_q^T + b_q[col]
  gemm_bt<2, true, false><<<dim3(8, 8, 16), dim3(256), 0, stream>>>(
      xnT, wqkv_b, qbuf, b_qkv, nullptr, nullptr,
      1024, 512, 512, 524288LL, 0LL, 524288LL);

  // 5: xEF[b] = [Et;Ft] (512x1024) * xnc[b]^T -> [k(512)][c(512)]
  gemm_bt<0, true, false><<<dim3(4, 8, 16), dim3(256), 0, stream>>>(
      etft, xnc, xEF, nullptr, nullptr, nullptr,
      512, 512, 1024, 0LL, 524288LL, 262144LL);

  // 6: kp[b][k][c'] = xE[b] (256x512) * w_k^T + esum[k]*b_k[c']
  gemm_bt<3, true, false><<<dim3(2, 8, 16), dim3(256), 0, stream>>>(
      xEF, wqkv_b + 262144, kpb, esum, b_qkv + 512, nullptr,
      256, 512, 512, 262144LL, 0LL, 131072LL);

  // 7: vp[b][c'][k] = w_v (512x512) * xF[b]^T + b_v[c']*fsum[k]
  gemm_bt<3, true, false><<<dim3(4, 4, 16), dim3(256), 0, stream>>>(
      wqkv_b + 524288, xEF + 131072, vpb, b_qkv + 1024, fsum, nullptr,
      512, 256, 512, 0LL, 262144LL, 131072LL);

  // 8: attention
  attn_fused32<<<dim3(4, 8, 16), dim3(512), 0, stream>>>(qbuf, kpb, vpb, attno);

  // 9: S5: out[b][o][n] = wcomb * attno[b]^T + b2[row] + xnc
  gemm_bt<1, false, true><<<dim3(4, 16, 16), dim3(256), 0, stream>>>(
      wcomb_b, attno, out, b2, nullptr, xnc,
      512, 1024, 512, 0LL, 524288LL, 524288LL);
}

// Round 14
// 130.792 us; speedup vs baseline: 1.2410x; 1.0564x over previous
//
#include <hip/hip_runtime.h>
#include <hip/hip_bf16.h>

#define B_ 16
#define C_ 512
#define N_ 1024
#define KL 256
#define HEADS_ 8
#define DH_ 64

typedef __attribute__((ext_vector_type(8))) short bf16x8;
typedef __attribute__((ext_vector_type(4))) float f32x4;
typedef __attribute__((ext_vector_type(16))) float f32x16;

__device__ inline short f2bf(float f) {
  __hip_bfloat16 h = __float2bfloat16(f);
  return *reinterpret_cast<short*>(&h);
}

__device__ inline float bf2f(short s) {
  union { unsigned int u; float f; } c;
  c.u = ((unsigned int)(unsigned short)s) << 16;
  return c.f;
}

__device__ inline void gload16(const void* g, void* l) {
  __builtin_amdgcn_global_load_lds(
      (const __attribute__((address_space(1))) void*)g,
      (__attribute__((address_space(3))) void*)l, 16, 0, 0);
}

// ---------------- merged: GN stats pass1 (blocks 0..1023) + weight prep (1024..1289)
__global__ __launch_bounds__(256) void stats_prep(
    const float* __restrict__ x, float2* __restrict__ part,
    const float* __restrict__ w_qkv, const float* __restrict__ w_proj,
    const float* __restrict__ w_o, const float* __restrict__ E,
    const float* __restrict__ F, const float* __restrict__ b_o,
    const float* __restrict__ b_proj,
    short* __restrict__ wqkv_b, short* __restrict__ wproj_b,
    short* __restrict__ woT_b, short* __restrict__ Et, short* __restrict__ Ft,
    float* __restrict__ esum, float* __restrict__ fsum, float* __restrict__ b2) {
  __shared__ float tl[64 * 65];
  __shared__ float red[8];
  __shared__ float cs[4][64];
  int bid = blockIdx.x;
  const int tid = threadIdx.x;

  if (bid < 1024) {  // GN stats slice
    const int lane = tid & 63, wid = tid >> 6;
    const float4* b4 = (const float4*)(x + (long long)bid * 8192);
    float s = 0.f, sq = 0.f;
#pragma unroll
    for (int j = 0; j < 8; ++j) {
      float4 v = b4[tid + j * 256];
      s += v.x + v.y + v.z + v.w;
      sq += v.x * v.x + v.y * v.y + v.z * v.z + v.w * v.w;
    }
#pragma unroll
    for (int m = 1; m < 64; m <<= 1) {
      s += __shfl_xor(s, m);
      sq += __shfl_xor(sq, m);
    }
    if (lane == 0) { red[wid] = s; red[4 + wid] = sq; }
    __syncthreads();
    if (tid == 0)
      part[bid] = make_float2(red[0] + red[1] + red[2] + red[3],
                              red[4] + red[5] + red[6] + red[7]);
    return;
  }
  bid -= 1024;

  if (bid < 64) {  // dtype converts
    const float4* src;
    short4* dst;
    if (bid < 48) { src = (const float4*)w_qkv + bid * 4096; dst = (short4*)wqkv_b + bid * 4096; }
    else          { src = (const float4*)w_proj + (bid - 48) * 4096; dst = (short4*)wproj_b + (bid - 48) * 4096; }
#pragma unroll
    for (int i = 0; i < 16; ++i) {
      float4 v = src[tid + i * 256];
      short4 p; p.x = f2bf(v.x); p.y = f2bf(v.y); p.z = f2bf(v.z); p.w = f2bf(v.w);
      dst[tid + i * 256] = p;
    }
    return;
  }
  bid -= 64;
  if (bid < 192) {  // transposes: w_o (64), E (64), F (64)
    const float* src; short* dst; int sN, tr, tc;
    if (bid < 64) { src = w_o; dst = woT_b; sN = 512; tr = bid >> 3; tc = bid & 7; }
    else if (bid < 128) { src = E; dst = Et; sN = 256; tr = (bid - 64) & 15; tc = (bid - 64) >> 4; }
    else { src = F; dst = Ft; sN = 256; tr = (bid - 128) & 15; tc = (bid - 128) >> 4; }
    const int R = (sN == 512) ? 512 : 1024;
#pragma unroll 4
    for (int i = 0; i < 16; ++i) {
      const int idx = tid + i * 256;
      const int rl = idx >> 6, cl = idx & 63;
      tl[rl * 65 + cl] = src[(tr * 64 + rl) * sN + tc * 64 + cl];
    }
    __syncthreads();
#pragma unroll 4
    for (int i = 0; i < 16; ++i) {
      const int idx = tid + i * 256;
      const int cl = idx >> 6, rl = idx & 63;
      dst[(tc * 64 + cl) * R + tr * 64 + rl] = f2bf(tl[rl * 65 + cl]);
    }
    return;
  }
  bid -= 192;
  if (bid < 8) {  // colsum
    const float* src = (bid < 4) ? E : F;
    float* dst = (bid < 4) ? esum : fsum;
    const int cb = (bid & 3) * 64;
    const int col = cb + (tid & 63), seg = tid >> 6;
    float s = 0.f;
    for (int n = seg * 256; n < seg * 256 + 256; ++n) s += src[n * 256 + col];
    cs[seg][tid & 63] = s;
    __syncthreads();
    if (tid < 64) dst[cb + tid] = cs[0][tid] + cs[1][tid] + cs[2][tid] + cs[3][tid];
    return;
  }
  bid -= 8;
  {  // b2
    const int o = bid * 256 + tid;
    float s = b_proj[o];
    for (int m = 0; m < 512; ++m) s += w_proj[o * 512 + m] * b_o[m];
    b2[o] = s;
  }
}

// ---------------- GroupNorm apply (stats finalize inlined per block)
__global__ __launch_bounds__(256) void gn_apply(
    const float* __restrict__ x, const float* __restrict__ gamma,
    const float* __restrict__ beta, const float2* __restrict__ part,
    short* __restrict__ xnc, short* __restrict__ xnT) {
  const int t = blockIdx.x, g = blockIdx.y, b = blockIdx.z;
  float s = 0.f, sq = 0.f;
#pragma unroll
  for (int j = 0; j < 8; ++j) {
    float2 p = part[(b * 8 + g) * 8 + j];
    s += p.x; sq += p.y;
  }
  const float mu = s * (1.f / 65536.f);
  const float var = sq * (1.f / 65536.f) - mu * mu;
  const float rs = rsqrtf(var + 1e-5f);

  __shared__ short tile[64 * 65];
#pragma unroll
  for (int i = 0; i < 4; ++i) {
    const int idx = threadIdx.x + i * 256;
    const int cl = idx >> 4;
    const int nl0 = (idx & 15) * 4;
    const int ch = g * 64 + cl;
    const long long gi = ((long long)(b * C_ + ch)) * N_ + t * 64 + nl0;
    const float4 v = *(const float4*)(x + gi);
    const float gm = gamma[ch], bt = beta[ch];
    short s0 = f2bf((v.x - mu) * rs * gm + bt);
    short s1 = f2bf((v.y - mu) * rs * gm + bt);
    short s2 = f2bf((v.z - mu) * rs * gm + bt);
    short s3 = f2bf((v.w - mu) * rs * gm + bt);
    short4 pk; pk.x = s0; pk.y = s1; pk.z = s2; pk.w = s3;
    *(short4*)(xnc + gi) = pk;
    tile[cl * 65 + nl0] = s0;
    tile[cl * 65 + nl0 + 1] = s1;
    tile[cl * 65 + nl0 + 2] = s2;
    tile[cl * 65 + nl0 + 3] = s3;
  }
  __syncthreads();

#pragma unroll
  for (int i = 0; i < 4; ++i) {
    const int idx = threadIdx.x + i * 256;
    const int cl0 = (idx & 15) * 4;
    const int nl = idx >> 4;
    short4 pk;
    pk.x = tile[(cl0 + 0) * 65 + nl];
    pk.y = tile[(cl0 + 1) * 65 + nl];
    pk.z = tile[(cl0 + 2) * 65 + nl];
    pk.w = tile[(cl0 + 3) * 65 + nl];
    *(short4*)(xnT + ((long long)b * N_ + t * 64 + nl) * C_ + g * 64 + cl0) = pk;
  }
}

// ---------------- generic GEMM: C[M][Nn] = A (M x Kd) * Bt (Nn x Kd)^T
// Template BM in {128, 64}, BN fixed 64. BM=64 gives 16 KB LDS and 2x more
// blocks -> continues the r13-validated residency push for the small/skinny
// GEMMs (xEF/kp/vp/wcomb were at 1-2 blocks/CU). Single-buffered 2-barrier
// loop (r11-proven), bijective XCD chunk swizzle (nblk % 8 == 0).
// BIAS_MODE: 0 none, 1 bias[row], 2 bias[col], 3 bias[row]*bias2[col].
template <int BM, int BIAS_MODE, bool OUT_BF16, bool RESID>
__global__ __launch_bounds__(256) void gemm_bt(
    const short* __restrict__ A, const short* __restrict__ Bt,
    void* __restrict__ Cout, const float* __restrict__ bias,
    const float* __restrict__ bias2, const short* __restrict__ resid,
    int M, int Nn, int Kd, long long sA, long long sB, long long sC) {
  constexpr int AR = BM / 32;      // A-stage iters == m-frags per wave
  constexpr int WR = BM / 2;       // rows per wave-row-half
  const int gx = gridDim.x, gy = gridDim.y;
  const int nwg = gx * gy * gridDim.z;
  const int bid = blockIdx.x + gx * (blockIdx.y + gy * blockIdx.z);
  const int cpx = nwg >> 3;
  int w = (bid & 7) * cpx + (bid >> 3);
  const int mx = w % gx; w /= gx;
  const int ny = w % gy;
  const int bz = w / gy;

  const int m0 = mx * BM;
  const int n0 = ny * 64;
  const short* Ab = A + bz * sA;
  const short* Bb = Bt + bz * sB;
  const int tid = threadIdx.x;
  const int lane = tid & 63;
  const int wid = tid >> 6;
  const int wm = wid >> 1, wn = wid & 1;

  __shared__ __align__(16) short As[BM * 64];
  __shared__ __align__(16) short Bs[64 * 64];

  f32x4 acc[AR][2] = {};

  for (int kt = 0; kt < Kd; kt += 64) {
#pragma unroll
    for (int r = 0; r < AR; ++r) {
      const int dbase = r * 4096 + wid * 1024;
      const int dbyte = dbase + (lane << 4);
      const int row = dbyte >> 7;
      const int chunk = ((dbyte >> 4) & 7) ^ (row & 7);
      gload16(Ab + (long long)(m0 + row) * Kd + kt + chunk * 8, (char*)As + dbase);
    }
#pragma unroll
    for (int r = 0; r < 2; ++r) {
      const int dbase = r * 4096 + wid * 1024;
      const int dbyte = dbase + (lane << 4);
      const int row = dbyte >> 7;
      const int chunk = ((dbyte >> 4) & 7) ^ (row & 7);
      gload16(Bb + (long long)(n0 + row) * Kd + kt + chunk * 8, (char*)Bs + dbase);
    }
    __syncthreads();
#pragma unroll
    for (int kk = 0; kk < 2; ++kk) {
      bf16x8 af[AR], bfr[2];
#pragma unroll
      for (int mi = 0; mi < AR; ++mi) {
        int row = wm * WR + mi * 16 + (lane & 15);
        int chunk = (kk * 4 + (lane >> 4)) ^ (row & 7);
        af[mi] = *(const bf16x8*)(As + row * 64 + chunk * 8);
      }
#pragma unroll
      for (int ni = 0; ni < 2; ++ni) {
        int row = wn * 32 + ni * 16 + (lane & 15);
        int chunk = (kk * 4 + (lane >> 4)) ^ (row & 7);
        bfr[ni] = *(const bf16x8*)(Bs + row * 64 + chunk * 8);
      }
#pragma unroll
      for (int mi = 0; mi < AR; ++mi)
#pragma unroll
        for (int ni = 0; ni < 2; ++ni)
          acc[mi][ni] = __builtin_amdgcn_mfma_f32_16x16x32_bf16(af[mi], bfr[ni], acc[mi][ni], 0, 0, 0);
    }
    __syncthreads();
  }

#pragma unroll
  for (int mi = 0; mi < AR; ++mi) {
#pragma unroll
    for (int ni = 0; ni < 2; ++ni) {
      const int row = m0 + wm * WR + mi * 16 + ((lane >> 4) << 2);
      const int col = n0 + wn * 32 + ni * 16 + (lane & 15);
      f32x4 v = acc[mi][ni];
#pragma unroll
      for (int j = 0; j < 4; ++j) {
        float val = v[j];
        if (BIAS_MODE == 1) val += bias[row + j];
        if (BIAS_MODE == 2) val += bias[col];
        if (BIAS_MODE == 3) val += bias[row + j] * bias2[col];
        const long long ci = (long long)bz * sC + (long long)(row + j) * Nn + col;
        if (RESID) val += bf2f(resid[ci]);
        if (OUT_BF16) ((short*)Cout)[ci] = f2bf(val);
        else ((float*)Cout)[ci] = val;
      }
    }
  }
}

// ---------------- fused Linformer attention, 32x32 swapped-QK, in-register softmax
__global__ __launch_bounds__(512, 4) void attn_fused32(
    const short* __restrict__ q, const short* __restrict__ kp,
    const short* __restrict__ vp, short* __restrict__ o) {
  const int qt = blockIdx.x;
  const int h = blockIdx.y;
  const int b = blockIdx.z;
  const int tid = threadIdx.x;
  const int lane = tid & 63;
  const int wid = tid >> 6;
  const int nlo = lane & 31;
  const int hi = lane >> 5;

  __shared__ __align__(16) short kbuf[256 * 64];
  __shared__ __align__(16) short vbuf[64 * 256];

  {
    const short* base = kp + (long long)b * (KL * C_) + h * DH_;
#pragma unroll
    for (int i = 0; i < 4; ++i) {
      const int dbyte = (i * 512 + tid) * 16;
      const int row = dbyte >> 7;
      const int chunk = ((dbyte >> 4) & 7) ^ (row & 7);
      gload16(base + row * C_ + chunk * 8, (char*)kbuf + dbyte);
    }
  }
  {
    const short* base = vp + ((long long)b * C_ + h * DH_) * KL;
#pragma unroll
    for (int i = 0; i < 4; ++i) {
      const int dbyte = (i * 512 + tid) * 16;
      const int row = dbyte >> 9;
      const int chunk = ((dbyte >> 4) & 31) ^ (row & 7);
      gload16(base + row * KL + chunk * 8, (char*)vbuf + dbyte);
    }
  }

  const int n0 = qt * 256 + wid * 32;
  bf16x8 bq[4];
  {
    const short* qb = q + ((long long)b * N_ + n0 + nlo) * C_ + h * DH_ + hi * 8;
#pragma unroll
    for (int dk = 0; dk < 4; ++dk) bq[dk] = *(const bf16x8*)(qb + dk * 16);
  }
  __syncthreads();

  f32x16 oa0, oa1;
#pragma unroll
  for (int r = 0; r < 16; ++r) { oa0[r] = 0.f; oa1[r] = 0.f; }
  float mrun = -1e30f, lrun = 0.f;

#pragma unroll
  for (int kb = 0; kb < 8; ++kb) {
    f32x16 s;
#pragma unroll
    for (int r = 0; r < 16; ++r) s[r] = 0.f;
#pragma unroll
    for (int dk = 0; dk < 4; ++dk) {
      const int row = kb * 32 + nlo;
      bf16x8 ak = *(const bf16x8*)(kbuf + row * 64 + (((dk * 2 + hi) ^ (nlo & 7)) * 8));
      s = __builtin_amdgcn_mfma_f32_32x32x16_bf16(ak, bq[dk], s, 0, 0, 0);
    }
    float lm = -1e30f;
#pragma unroll
    for (int r = 0; r < 16; ++r) { s[r] *= 0.125f; lm = fmaxf(lm, s[r]); }
    lm = fmaxf(lm, __shfl_xor(lm, 32));
    const float mnew = fmaxf(mrun, lm);
    const float sc_old = __expf(mrun - mnew);
    float ls = 0.f;
#pragma unroll
    for (int r = 0; r < 16; ++r) {
      float p = __expf(s[r] - mnew);
      s[r] = p;
      ls += p;
    }
    ls += __shfl_xor(ls, 32);
    lrun = lrun * sc_old + ls;
    mrun = mnew;
#pragma unroll
    for (int r = 0; r < 16; ++r) { oa0[r] *= sc_old; oa1[r] *= sc_old; }

    unsigned int w[8];
#pragma unroll
    for (int i = 0; i < 8; ++i) {
      float plo = s[2 * i], phi = s[2 * i + 1];
      unsigned int pk;
      asm("v_cvt_pk_bf16_f32 %0, %1, %2" : "=v"(pk) : "v"(plo), "v"(phi));
      w[i] = pk;
    }
#pragma unroll
    for (int m = 0; m < 2; ++m) {
      unsigned int u0 = w[4 * m + 0], u1 = w[4 * m + 1];
      unsigned int u2 = w[4 * m + 2], u3 = w[4 * m + 3];
      asm volatile("v_permlane32_swap_b32 %0, %1" : "+v"(u0), "+v"(u2));
      asm volatile("v_permlane32_swap_b32 %0, %1" : "+v"(u1), "+v"(u3));
      union { unsigned int u[4]; bf16x8 v; } bp;
      bp.u[0] = u0; bp.u[1] = u1; bp.u[2] = u2; bp.u[3] = u3;
      const int ck = ((kb * 4 + m * 2 + hi) ^ (nlo & 7)) * 8;
      bf16x8 av0 = *(const bf16x8*)(vbuf + (nlo) * 256 + ck);
      bf16x8 av1 = *(const bf16x8*)(vbuf + (32 + nlo) * 256 + ck);
      oa0 = __builtin_amdgcn_mfma_f32_32x32x16_bf16(av0, bp.v, oa0, 0, 0, 0);
      oa1 = __builtin_amdgcn_mfma_f32_32x32x16_bf16(av1, bp.v, oa1, 0, 0, 0);
    }
  }

  const float rinv = 1.f / lrun;
  short* ob = o + ((long long)b * N_ + n0 + nlo) * C_ + h * DH_;
#pragma unroll
  for (int a = 0; a < 4; ++a) {
    short4 p0, p1;
    p0.x = f2bf(oa0[4 * a + 0] * rinv); p0.y = f2bf(oa0[4 * a + 1] * rinv);
    p0.z = f2bf(oa0[4 * a + 2] * rinv); p0.w = f2bf(oa0[4 * a + 3] * rinv);
    p1.x = f2bf(oa1[4 * a + 0] * rinv); p1.y = f2bf(oa1[4 * a + 1] * rinv);
    p1.z = f2bf(oa1[4 * a + 2] * rinv); p1.w = f2bf(oa1[4 * a + 3] * rinv);
    *(short4*)(ob + a * 8 + hi * 4) = p0;
    *(short4*)(ob + 32 + a * 8 + hi * 4) = p1;
  }
}

extern "C" void kernel_launch(void* const* d_in, const int* in_sizes, int n_in,
                              void* d_out, int out_size, void* d_ws, size_t ws_size,
                              hipStream_t stream) {
  (void)in_sizes; (void)n_in; (void)out_size; (void)ws_size;
  const float* x      = (const float*)d_in[0];
  const float* gamma  = (const float*)d_in[1];
  const float* beta   = (const float*)d_in[2];
  const float* w_qkv  = (const float*)d_in[3];
  const float* b_qkv  = (const float*)d_in[4];
  const float* E      = (const float*)d_in[5];
  const float* F      = (const float*)d_in[6];
  const float* w_o    = (const float*)d_in[7];
  const float* b_o    = (const float*)d_in[8];
  const float* w_proj = (const float*)d_in[9];
  const float* b_proj = (const float*)d_in[10];
  float* out = (float*)d_out;

  char* ws = (char*)d_ws;
  short* xnc    = (short*)ws;  ws += 16777216LL;   // [16][512][1024] bf16
  short* xnT    = (short*)ws;  ws += 16777216LL;   // [16][1024][512] bf16 (later: attno)
  short* qbuf   = (short*)ws;  ws += 16777216LL;   // [16][1024][512] bf16
  short* xEF    = (short*)ws;  ws += 8388608LL;    // [16][512][512] bf16 (xE 0-255, xF 256-511)
  short* kpb    = (short*)ws;  ws += 4194304LL;    // [16][256][512] bf16
  short* vpb    = (short*)ws;  ws += 4194304LL;    // [16][512][256] bf16
  short* wqkv_b = (short*)ws;  ws += 1572864LL;    // [1536][512] bf16
  short* wproj_b= (short*)ws;  ws += 524288LL;     // [512][512] bf16
  short* woT_b  = (short*)ws;  ws += 524288LL;     // [512][512] bf16 (w_o^T)
  short* wcomb_b= (short*)ws;  ws += 524288LL;     // [512][512] bf16 (w_proj*w_o)
  short* etft   = (short*)ws;  ws += 1048576LL;    // [512][1024] bf16 (Et; Ft at +256 rows)
  float2* part  = (float2*)ws; ws += 8192LL;       // [1024]
  float* esum   = (float*)ws;  ws += 1024LL;       // [256]
  float* fsum   = (float*)ws;  ws += 1024LL;       // [256]
  float* b2     = (float*)ws;  ws += 2048LL;       // [512]
  short* attno  = xnT;                             // alias
  short* Et     = etft;
  short* Ft     = etft + 262144;

  // 1: GN stats + ALL weight prep
  stats_prep<<<dim3(1290), dim3(256), 0, stream>>>(
      x, part, w_qkv, w_proj, w_o, E, F, b_o, b_proj,
      wqkv_b, wproj_b, woT_b, Et, Ft, esum, fsum, b2);

  // 2: GN apply
  gn_apply<<<dim3(16, 8, 16), dim3(256), 0, stream>>>(x, gamma, beta, part, xnc, xnT);

  // 3: wcomb = w_proj * w_o   (64x64 tiles: 64 blocks)
  gemm_bt<64, 0, true, false><<<dim3(8, 8, 1), dim3(256), 0, stream>>>(
      wproj_b, woT_b, wcomb_b, nullptr, nullptr, nullptr,
      512, 512, 512, 0LL, 0LL, 0LL);

  // 4: q[b][n][o] = xnT[b] * w_q^T + b_q[col]   (128x64: 1024 blocks, 4/CU)
  gemm_bt<128, 2, true, false><<<dim3(8, 8, 16), dim3(256), 0, stream>>>(
      xnT, wqkv_b, qbuf, b_qkv, nullptr, nullptr,
      1024, 512, 512, 524288LL, 0LL, 524288LL);

  // 5: xEF[b] = [Et;Ft] * xnc[b]^T   (64x64: 1024 blocks, 4/CU)
  gemm_bt<64, 0, true, false><<<dim3(8, 8, 16), dim3(256), 0, stream>>>(
      etft, xnc, xEF, nullptr, nullptr, nullptr,
      512, 512, 1024, 0LL, 524288LL, 262144LL);

  // 6: kp[b][k][c'] = xE[b] * w_k^T + esum[k]*b_k[c']   (64x64: 512 blocks)
  gemm_bt<64, 3, true, false><<<dim3(4, 8, 16), dim3(256), 0, stream>>>(
      xEF, wqkv_b + 262144, kpb, esum, b_qkv + 512, nullptr,
      256, 512, 512, 262144LL, 0LL, 131072LL);

  // 7: vp[b][c'][k] = w_v * xF[b]^T + b_v[c']*fsum[k]   (64x64: 512 blocks)
  gemm_bt<64, 3, true, false><<<dim3(8, 4, 16), dim3(256), 0, stream>>>(
      wqkv_b + 524288, xEF + 131072, vpb, b_qkv + 1024, fsum, nullptr,
      512, 256, 512, 0LL, 262144LL, 131072LL);

  // 8: attention
  attn_fused32<<<dim3(4, 8, 16), dim3(512), 0, stream>>>(qbuf, kpb, vpb, attno);

  // 9: S5: out[b][o][n] = wcomb * attno[b]^T + b2[row] + xnc   (128x64: 1024 blocks)
  gemm_bt<128, 1, false, true><<<dim3(4, 16, 16), dim3(256), 0, stream>>>(
      wcomb_b, attno, out, b2, nullptr, xnc,
      512, 1024, 512, 0LL, 524288LL, 524288LL);
}